// Round 14
// baseline (3685.454 us; speedup 1.0000x reference)
//
#include <hip/hip_runtime.h>

// Problem constants: B=8, N=16384, S=1024, T=2, D=3
#define NPTS 16384
#define SPTS 1024

typedef _Float16 half8 __attribute__((ext_vector_type(8)));
typedef float float16 __attribute__((ext_vector_type(16)));

union H8 { _Float16 h[8]; half8 v; uint4 q4; };

// min across each 32-lane half (validated r6-r13, absmax 0)
__device__ inline float wave32_min(float v) {
    v = fminf(v, __int_as_float(__builtin_amdgcn_mov_dpp(__float_as_int(v), 0xB1, 0xF, 0xF, true)));
    v = fminf(v, __int_as_float(__builtin_amdgcn_mov_dpp(__float_as_int(v), 0x4E, 0xF, 0xF, true)));
    v = fminf(v, __int_as_float(__builtin_amdgcn_mov_dpp(__float_as_int(v), 0x141, 0xF, 0xF, true)));
    v = fminf(v, __int_as_float(__builtin_amdgcn_mov_dpp(__float_as_int(v), 0x140, 0xF, 0xF, true)));
    v = fminf(v, __int_as_float(__builtin_amdgcn_ds_swizzle(__float_as_int(v), 0x401F)));
    return v;
}

// balanced 16->1 min tree (folds to v_min3_f32)
__device__ inline float tree16(const float16& d) {
    float m0 = fminf(d[0], d[1]),   m1 = fminf(d[2], d[3]);
    float m2 = fminf(d[4], d[5]),   m3 = fminf(d[6], d[7]);
    float m4 = fminf(d[8], d[9]),   m5 = fminf(d[10], d[11]);
    float m6 = fminf(d[12], d[13]), m7 = fminf(d[14], d[15]);
    float n0 = fminf(m0, m1), n1 = fminf(m2, m3);
    float n2 = fminf(m4, m5), n3 = fminf(m6, m7);
    return fminf(fminf(n0, n1), fminf(n2, n3));
}

// D[m][n] = A(gt)[m]·B(sp)[n], A=[x,y,z,|q|^2,1,0..], B=[-2x',-2y',-2z',1,|p'|^2,0..]
// One 32x32x16 f16 MFMA = 1024 exact sq-distances (fp32 acc; validated r6-r13).
// C layout: col=lane&31, row=(reg&3)+8*(reg>>2)+4*(lane>>5).
// r8/r12: NEVER tighten launch_bounds past (256,3) — catastrophic spill cliff.
// r13: traffic is NOT the limiter (3.6 MB fetch, same dur). Limiter = per-iter
// exposed LDS latency (1 ds_read per MFMA-pair + in-loop LDS atomics on lgkmcnt).
// This round: B-frags in REGISTERS (8 tiles/wave, 32 VGPRs) -> 1 ds_read per
// 8 independent MFMAs; no LDS atomics in loop; col-min wave-private (cm0..7);
// min encoding 0x7F7F7F7F - bits(v) + atomicMax -> single zero-memset for ws.

__global__ __launch_bounds__(256, 3) void fused_kernel(
    const float* __restrict__ gt,   // [8,16384,3]
    const float* __restrict__ sp,   // [8,1024,3]
    const float* __restrict__ tgt,  // [16,16384,3]
    const float* __restrict__ tsp,  // [16,1024,3]
    const float* __restrict__ tm,   // [2,3,3]
    float* __restrict__ accum,
    unsigned int* __restrict__ minarr)  // [24*1024], zero-init, stores 0x7F7F7F7F-bits
{
    const int bid = blockIdx.x;
    const int tid = threadIdx.x;
    const int lane = tid & 63;
    const int lh = lane & 31;
    const int w = tid >> 6;  // wave 0..3

    if (bid >= 1536) {
        // ---------------- consistency MSE (fp32 exact), tail blocks ----------------
        int idx = (bid - 1536) * 256 + tid;  // over (t,b,s) = 2*8*1024
        int t = idx >> 13;
        int bs = idx & 8191;
        const float* p = sp + (size_t)bs * 3;
        float x = p[0], y = p[1], z = p[2];
        const float* m = tm + t * 9;
        const float* q = tsp + (size_t)idx * 3;
        float acc = 0.f;
#pragma unroll
        for (int e = 0; e < 3; e++) {
            float v = fmaf(x, m[e], fmaf(y, m[3 + e], z * m[6 + e]));
            float d = v - q[e];
            acc = fmaf(d, d, acc);
        }
        for (int o = 32; o > 0; o >>= 1) acc += __shfl_down(acc, o, 64);
        if ((tid & 63) == 0)
            atomicAdd(accum, acc * (1000.f / (2.f * 8.f * 1024.f * 3.f)));
        return;
    }

    __shared__ uint4 s_afrag[264];       // 8 gt tiles * 33 uint4 = 4.2 KB
    __shared__ float s_rowmin[4 * 256];  // [wave][row] partial row-mins = 4 KB

    int bb = bid >> 6;   // 24 batches (consecutive 64 bids share batch -> L2 reuse)
    int mc = bid & 63;   // 256-row gt chunk
    const float* spp = (bb < 8) ? sp + (size_t)bb * SPTS * 3
                                : tsp + (size_t)(bb - 8) * SPTS * 3;
    const float* qp  = (bb < 8) ? gt + (size_t)bb * NPTS * 3
                                : tgt + (size_t)(bb - 8) * NPTS * 3;

    // B-frags in registers: wave w owns sp points [w*256, w*256+256) as 8 tiles
    H8 b0, b1, b2, b3, b4, b5, b6, b7;
#define LOADB(J, BJ) { BJ.q4 = make_uint4(0, 0, 0, 0); if (lane < 32) {            \
        const float* pp = spp + (size_t)(w * 256 + (J) * 32 + lh) * 3;             \
        float sx = pp[0], sy = pp[1], sz = pp[2];                                  \
        BJ.h[0] = (_Float16)(-2.f * sx); BJ.h[1] = (_Float16)(-2.f * sy);          \
        BJ.h[2] = (_Float16)(-2.f * sz); BJ.h[3] = (_Float16)1.f;                  \
        BJ.h[4] = (_Float16)(sx * sx + sy * sy + sz * sz); } }
    LOADB(0, b0) LOADB(1, b1) LOADB(2, b2) LOADB(3, b3)
    LOADB(4, b4) LOADB(5, b5) LOADB(6, b6) LOADB(7, b7)
#undef LOADB

    // stage A-frags (256 gt rows), one per thread, + zero slots
    if (tid < 8) s_afrag[tid * 33 + 32] = make_uint4(0, 0, 0, 0);
    {
        const float* pp = qp + (size_t)(mc * 256 + tid) * 3;
        float x = pp[0], y = pp[1], z = pp[2];
        H8 af; af.q4 = make_uint4(0, 0, 0, 0);
        af.h[0] = (_Float16)x; af.h[1] = (_Float16)y; af.h[2] = (_Float16)z;
        af.h[3] = (_Float16)(x * x + y * y + z * z); af.h[4] = (_Float16)1.f;
        s_afrag[(tid >> 5) * 33 + (tid & 31)] = af.q4;
    }
    __syncthreads();

    const char* aBase = (const char*)s_afrag + ((lane < 32) ? lh * 16 : 512);
    float16 z16 = {0.f,0.f,0.f,0.f,0.f,0.f,0.f,0.f,0.f,0.f,0.f,0.f,0.f,0.f,0.f,0.f};
    float cm0 = 1e30f, cm1 = 1e30f, cm2 = 1e30f, cm3 = 1e30f;
    float cm4 = 1e30f, cm5 = 1e30f, cm6 = 1e30f, cm7 = 1e30f;
    const int h4 = (lane >> 5) << 2;  // 4*h in the row formula

#pragma unroll
    for (int m = 0; m < 8; m++) {
        H8 a; a.q4 = *(const uint4*)(aBase + m * 528);
        float16 d0 = __builtin_amdgcn_mfma_f32_32x32x16_f16(a.v, b0.v, z16, 0, 0, 0);
        float16 d1 = __builtin_amdgcn_mfma_f32_32x32x16_f16(a.v, b1.v, z16, 0, 0, 0);
        float16 d2 = __builtin_amdgcn_mfma_f32_32x32x16_f16(a.v, b2.v, z16, 0, 0, 0);
        float16 d3 = __builtin_amdgcn_mfma_f32_32x32x16_f16(a.v, b3.v, z16, 0, 0, 0);
        float16 d4 = __builtin_amdgcn_mfma_f32_32x32x16_f16(a.v, b4.v, z16, 0, 0, 0);
        float16 d5 = __builtin_amdgcn_mfma_f32_32x32x16_f16(a.v, b5.v, z16, 0, 0, 0);
        float16 d6 = __builtin_amdgcn_mfma_f32_32x32x16_f16(a.v, b6.v, z16, 0, 0, 0);
        float16 d7 = __builtin_amdgcn_mfma_f32_32x32x16_f16(a.v, b7.v, z16, 0, 0, 0);
        // row-min over this wave's 256 cols, then cross-lane reduce + store
#pragma unroll
        for (int r = 0; r < 16; r++) {
            float p0 = fminf(d0[r], d1[r]), p1 = fminf(d2[r], d3[r]);
            float p2 = fminf(d4[r], d5[r]), p3 = fminf(d6[r], d7[r]);
            float rv = fminf(fminf(p0, p1), fminf(p2, p3));
            float v = wave32_min(rv);
            if (lh == r)
                s_rowmin[w * 256 + m * 32 + (r & 3) + 8 * (r >> 2) + h4] = v;
        }
        // col-min accumulate (wave-private, complete over all m at loop end)
        cm0 = fminf(cm0, tree16(d0)); cm1 = fminf(cm1, tree16(d1));
        cm2 = fminf(cm2, tree16(d2)); cm3 = fminf(cm3, tree16(d3));
        cm4 = fminf(cm4, tree16(d4)); cm5 = fminf(cm5, tree16(d5));
        cm6 = fminf(cm6, tree16(d6)); cm7 = fminf(cm7, tree16(d7));
    }
    __syncthreads();

    // ---- row fold across waves + scaled sum -> accum ----
    {
        float v = fminf(fminf(s_rowmin[0 * 256 + tid], s_rowmin[1 * 256 + tid]),
                        fminf(s_rowmin[2 * 256 + tid], s_rowmin[3 * 256 + tid]));
        float scale = (bb < 8) ? 1.f / (2.f * 3.f * 8.f * 16384.f)
                               : 1.f / (2.f * 3.f * 16.f * 16384.f);
        float s = v * scale;
        for (int o = 32; o > 0; o >>= 1) s += __shfl_down(s, o, 64);
        if (lane == 0) atomicAdd(accum, s);
    }

    // ---- col-min -> global (encoded atomicMax, coalesced 32-wide) ----
#define STOREC(J, CJ) { float vv = fminf(CJ, __shfl_xor(CJ, 32, 64));              \
        if (lane < 32) atomicMax(&minarr[bb * SPTS + w * 256 + (J) * 32 + lh],     \
                                 0x7F7F7F7Fu - __float_as_uint(fmaxf(vv, 0.f))); }
    STOREC(0, cm0) STOREC(1, cm1) STOREC(2, cm2) STOREC(3, cm3)
    STOREC(4, cm4) STOREC(5, cm5) STOREC(6, cm6) STOREC(7, cm7)
#undef STOREC
}

// single block: decode minarr, fold into accum, write out
__global__ __launch_bounds__(256) void finalize_kernel(
    const unsigned int* __restrict__ minarr,
    const float* __restrict__ accum,
    float* __restrict__ out)
{
    float s = 0.f;
    for (int i = threadIdx.x; i < 24 * 1024; i += 256) {
        float v = __uint_as_float(0x7F7F7F7Fu - minarr[i]);
        int bb = i >> 10;
        float scale = (bb < 8) ? 1.f / (2.f * 3.f * 8.f * 1024.f)
                               : 1.f / (2.f * 3.f * 16.f * 1024.f);
        s = fmaf(v, scale, s);
    }
    for (int o = 32; o > 0; o >>= 1) s += __shfl_down(s, o, 64);
    __shared__ float fsum[4];
    if ((threadIdx.x & 63) == 0) fsum[threadIdx.x >> 6] = s;
    __syncthreads();
    if (threadIdx.x == 0) out[0] = accum[0] + fsum[0] + fsum[1] + fsum[2] + fsum[3];
}

extern "C" void kernel_launch(void* const* d_in, const int* in_sizes, int n_in,
                              void* d_out, int out_size, void* d_ws, size_t ws_size,
                              hipStream_t stream) {
    const float* gt  = (const float*)d_in[0];  // gt_points [8,16384,3]
    const float* sp  = (const float*)d_in[1];  // structure_points [8,1024,3]
    const float* tgt = (const float*)d_in[2];  // transed_gt_points [2,8,16384,3]
    const float* tsp = (const float*)d_in[3];  // transed_structure_points [2,8,1024,3]
    const float* tm  = (const float*)d_in[4];  // trans_mats [2,3,3]
    float* out = (float*)d_out;

    float* accum = (float*)d_ws;                              // 64 B
    unsigned int* minarr = (unsigned int*)((char*)d_ws + 64); // 96 KB

    // single memset: accum=0.0, minarr=0 (encodes +3.4e38 under 0x7F7F7F7F-bits)
    hipMemsetAsync(d_ws, 0, 64 + 24 * 1024 * sizeof(unsigned int), stream);

    fused_kernel<<<1600, 256, 0, stream>>>(gt, sp, tgt, tsp, tm, accum, minarr);
    finalize_kernel<<<1, 256, 0, stream>>>(minarr, accum, out);
}